// Round 6
// baseline (135.922 us; speedup 1.0000x reference)
//
#include <hip/hip_runtime.h>
#include <hip/hip_bf16.h>
#include <math.h>

#define N 8192
#define D 256
#define MARGIN 0.3f
#define EPS 1e-12f

#define BT 128                             // block tile (i and j)
#define BK 64                              // K chunk staged in LDS
#define NJB (N / BT)                       // 64 tile-blocks per dim
#define TOTAL_TRI (NJB * (NJB + 1) / 2)    // 2080 upper-triangle tiles

typedef __attribute__((ext_vector_type(8))) short short8;   // 8 bf16 in 4 VGPRs
typedef __attribute__((ext_vector_type(4))) float floatx4;  // MFMA C/D

static __device__ inline ushort f2bf(float f) {
    __hip_bfloat16 h = __float2bfloat16(f);
    return *reinterpret_cast<ushort*>(&h);
}

// async global->LDS, 16B per lane, dest = wave-uniform base + lane*16
static __device__ inline void gload_lds16(const void* g, void* l) {
    __builtin_amdgcn_global_load_lds((const __attribute__((address_space(1))) unsigned int*)g,
                                     (__attribute__((address_space(3))) unsigned int*)l,
                                     16, 0, 0);
}

// ---------------- Kernel 1: L2 normalize rows -> bf16 copy; zero the output ----------------
__global__ __launch_bounds__(256) void normalize_kernel(const float* __restrict__ x,
                                                        ushort* __restrict__ fn16,
                                                        float* __restrict__ out) {
    if (blockIdx.x == 0 && threadIdx.x == 0) out[0] = 0.0f;
    const int row  = blockIdx.x * 4 + (threadIdx.x >> 6);   // 1 wave per row
    const int lane = threadIdx.x & 63;
    float4 v = ((const float4*)(x + (size_t)row * D))[lane];
    float s = v.x * v.x + v.y * v.y + v.z * v.z + v.w * v.w;
    #pragma unroll
    for (int off = 32; off; off >>= 1) s += __shfl_down(s, off);
    s = __shfl(s, 0);
    const float inv = 1.0f / fmaxf(sqrtf(s), 1e-12f);
    ushort4 b;
    b.x = f2bf(v.x * inv); b.y = f2bf(v.y * inv);
    b.z = f2bf(v.z * inv); b.w = f2bf(v.w * inv);
    ((ushort4*)(fn16 + (size_t)row * D))[lane] = b;
}

// ---------------- Kernel 2: triangular dual-MFMA gram + col-layout-only epilogues ------------
// Upper-triangle tiles (jb >= ib). Reductions on g (post-norm ||f||^2==1, d2=2-2g monotone dec:
// hardest_pos = min g over positives, hardest_neg = max g over negatives).
// acc  = A.B^T -> column partials over the 128 i-rows -> slot ib, rows j.
// acc2 = B.A^T (offdiag only, fragments reused, MFMA pipe was idle) -> column partials over the
// 128 j-rows -> slot jb, rows i. Both epilogues are the cheap C-layout in-register reduction:
// no 16-lane shuffle chains. Every (slot,row) written exactly once: plain stores.
__global__ __launch_bounds__(256) void gram_kernel(const ushort* __restrict__ fn16,
                                                   const int* __restrict__ lab,
                                                   float* __restrict__ gp_part,
                                                   float* __restrict__ gn_part) {
    __shared__ ushort As[BT][BK];     // 16 KB, XOR-swizzled chunks
    __shared__ ushort Bs[BT][BK];     // 16 KB
    __shared__ float cGp[BT][2], cGn[BT][2];   // j-col partials, per wi half
    __shared__ float rGp[BT][2], rGn[BT][2];   // i-col partials, per wj half
    __shared__ int __attribute__((aligned(16))) labsI[BT];
    __shared__ int __attribute__((aligned(16))) labsJ[BT];

    // triangular decode: idx -> (ib, jb), row-major over jb >= ib
    const int idx = blockIdx.x;
    const float c = 2.0f * NJB + 1.0f;
    int ib = (int)((c - sqrtf(c * c - 8.0f * (float)idx)) * 0.5f);
    while (ib > 0 && idx < ib * NJB - ib * (ib - 1) / 2) ib--;
    while (idx >= (ib + 1) * NJB - (ib + 1) * ib / 2) ib++;
    const int jb = ib + (idx - (ib * NJB - ib * (ib - 1) / 2));
    const bool offdiag = (jb > ib);
    const int i0 = ib * BT, j0 = jb * BT;

    const int t    = threadIdx.x;
    const int w    = t >> 6;
    const int lane = t & 63;
    const int wi   = w >> 1, wj = w & 1;        // 2x2 waves, each 64x64
    const int quad = lane >> 4;
    const int l15  = lane & 15;

    if (t < BT) labsI[t] = lab[i0 + t];
    else        labsJ[t - BT] = lab[j0 + (t - BT)];

    floatx4 acc[4][4], acc2[4][4];
    #pragma unroll
    for (int m = 0; m < 4; m++)
        #pragma unroll
        for (int n = 0; n < 4; n++) {
            acc[m][n]  = (floatx4){0.f, 0.f, 0.f, 0.f};
            acc2[m][n] = (floatx4){0.f, 0.f, 0.f, 0.f};
        }

    const ushort (*Bsrc)[BK] = offdiag ? Bs : As;   // diagonal tile: B == A

    for (int kc = 0; kc < D; kc += BK) {
        __syncthreads();   // also covers label staging on first iteration
        #pragma unroll
        for (int q = 0; q < 4; q++) {
            const int s  = q * 256 + w * 64 + lane;
            const int r  = s >> 3;
            const int cl = (s & 7) ^ (r & 7);          // logical chunk for this phys slot
            const int base = (q * 256 + w * 64) * 8;
            gload_lds16(fn16 + (size_t)(i0 + r) * D + kc + cl * 8, (ushort*)As + base);
            if (offdiag)
                gload_lds16(fn16 + (size_t)(j0 + r) * D + kc + cl * 8, (ushort*)Bs + base);
        }
        __syncthreads();
        #pragma unroll
        for (int ks = 0; ks < 2; ks++) {
            short8 af[4], bf_[4];
            #pragma unroll
            for (int m = 0; m < 4; m++) {
                const int rr = wi * 64 + m * 16 + l15;
                const int cp = (ks * 4 + quad) ^ (rr & 7);
                af[m] = *(const short8*)(&As[rr][cp * 8]);
            }
            #pragma unroll
            for (int n = 0; n < 4; n++) {
                const int rr = wj * 64 + n * 16 + l15;
                const int cp = (ks * 4 + quad) ^ (rr & 7);
                bf_[n] = *(const short8*)(&Bsrc[rr][cp * 8]);
            }
            #pragma unroll
            for (int m = 0; m < 4; m++)
                #pragma unroll
                for (int n = 0; n < 4; n++)
                    acc[m][n] = __builtin_amdgcn_mfma_f32_16x16x32_bf16(af[m], bf_[n], acc[m][n], 0, 0, 0);
            if (offdiag) {
                #pragma unroll
                for (int n = 0; n < 4; n++)
                    #pragma unroll
                    for (int m = 0; m < 4; m++)
                        acc2[n][m] = __builtin_amdgcn_mfma_f32_16x16x32_bf16(bf_[n], af[m], acc2[n][m], 0, 0, 0);
            }
        }
    }
    __syncthreads();

    // ---- col-side epilogue from acc: element (m,n,r) = g[i = wi*64+m*16+quad*4+r][j = wj*64+n*16+l15]
    #pragma unroll
    for (int n = 0; n < 4; n++) {
        const int labj = labsJ[wj * 64 + n * 16 + l15];
        float pC = INFINITY, nC = -INFINITY;
        #pragma unroll
        for (int m = 0; m < 4; m++) {
            const int4 li4 = *(const int4*)(&labsI[wi * 64 + m * 16 + quad * 4]);
            const int labi[4] = {li4.x, li4.y, li4.z, li4.w};
            #pragma unroll
            for (int r = 0; r < 4; r++) {
                const float g = acc[m][n][r];
                const bool same = (labi[r] == labj);
                pC = fminf(pC, same ? g : INFINITY);
                nC = fmaxf(nC, same ? -INFINITY : g);
            }
        }
        pC = fminf(pC, __shfl_xor(pC, 16)); pC = fminf(pC, __shfl_xor(pC, 32));
        nC = fmaxf(nC, __shfl_xor(nC, 16)); nC = fmaxf(nC, __shfl_xor(nC, 32));
        if (quad == 0) {
            const int col = wj * 64 + n * 16 + l15;
            cGp[col][wi] = pC; cGn[col][wi] = nC;
        }
    }
    // ---- col-side epilogue from acc2 (offdiag): element (n,m,r) = g[j = wj*64+n*16+quad*4+r][i = wi*64+m*16+l15]
    if (offdiag) {
        #pragma unroll
        for (int m = 0; m < 4; m++) {
            const int labi = labsI[wi * 64 + m * 16 + l15];
            float pR = INFINITY, nR = -INFINITY;
            #pragma unroll
            for (int n = 0; n < 4; n++) {
                const int4 lj4 = *(const int4*)(&labsJ[wj * 64 + n * 16 + quad * 4]);
                const int labj[4] = {lj4.x, lj4.y, lj4.z, lj4.w};
                #pragma unroll
                for (int r = 0; r < 4; r++) {
                    const float g = acc2[n][m][r];
                    const bool same = (labj[r] == labi);
                    pR = fminf(pR, same ? g : INFINITY);
                    nR = fmaxf(nR, same ? -INFINITY : g);
                }
            }
            pR = fminf(pR, __shfl_xor(pR, 16)); pR = fminf(pR, __shfl_xor(pR, 32));
            nR = fmaxf(nR, __shfl_xor(nR, 16)); nR = fmaxf(nR, __shfl_xor(nR, 32));
            if (quad == 0) {
                const int col = wi * 64 + m * 16 + l15;
                rGp[col][wj] = pR; rGn[col][wj] = nR;
            }
        }
    }
    __syncthreads();
    if (t < BT) {
        gp_part[(size_t)ib * N + j0 + t] = fminf(cGp[t][0], cGp[t][1]);
        gn_part[(size_t)ib * N + j0 + t] = fmaxf(cGn[t][0], cGn[t][1]);
    } else if (offdiag) {
        const int i = t - BT;
        gp_part[(size_t)jb * N + i0 + i] = fminf(rGp[i][0], rGp[i][1]);
        gn_part[(size_t)jb * N + i0 + i] = fmaxf(rGn[i][0], rGn[i][1]);
    }
}

// ---------------- Kernel 3: fold slots, sqrt, relu, mean (one atomic per block) --------------
__global__ __launch_bounds__(256) void reduce_kernel(const float* __restrict__ gp_part,
                                                     const float* __restrict__ gn_part,
                                                     float* __restrict__ out) {
    const int i = blockIdx.x * 256 + threadIdx.x;   // 32 blocks x 256 = 8192 rows
    float gp = INFINITY, gn = -INFINITY;
    for (int s = 0; s < NJB; s++) {
        gp = fminf(gp, gp_part[(size_t)s * N + i]);
        gn = fmaxf(gn, gn_part[(size_t)s * N + i]);
    }
    const float dp = sqrtf(fmaxf(2.0f - 2.0f * gp, EPS));  // hardest_pos distance
    const float dn = sqrtf(fmaxf(2.0f - 2.0f * gn, EPS));  // hardest_neg distance
    const float l  = dp - dn + MARGIN;
    float sum = (l > 0.0f) ? l : 0.0f;
    #pragma unroll
    for (int off = 32; off; off >>= 1) sum += __shfl_down(sum, off);
    __shared__ float wsum[4];
    if ((threadIdx.x & 63) == 0) wsum[threadIdx.x >> 6] = sum;
    __syncthreads();
    if (threadIdx.x == 0)
        atomicAdd(out, (wsum[0] + wsum[1] + wsum[2] + wsum[3]) * (1.0f / (float)N));
}

extern "C" void kernel_launch(void* const* d_in, const int* in_sizes, int n_in,
                              void* d_out, int out_size, void* d_ws, size_t ws_size,
                              hipStream_t stream) {
    const float* x   = (const float*)d_in[0];
    const int*   lab = (const int*)d_in[1];
    float* out = (float*)d_out;

    char* ws = (char*)d_ws;
    ushort* fn16    = (ushort*)ws;                                  // N*D bf16 = 4 MB
    float*  gp_part = (float*)(ws + (size_t)N * D * 2);             // NJB*N floats = 2 MB
    float*  gn_part = gp_part + (size_t)NJB * N;                    // NJB*N floats = 2 MB

    normalize_kernel<<<N / 4, 256, 0, stream>>>(x, fn16, out);
    gram_kernel<<<TOTAL_TRI, 256, 0, stream>>>(fn16, lab, gp_part, gn_part);
    reduce_kernel<<<N / 256, 256, 0, stream>>>(gp_part, gn_part, out);
}